// Round 22
// baseline (442.379 us; speedup 1.0000x reference)
//
#include <hip/hip_runtime.h>
#include <math.h>

#define LSEQ 4096
#define DIMC 256
#define DI   512
#define NCH  128    // chunks over L
#define CHL  32     // chunk length

typedef short short8 __attribute__((ext_vector_type(8)));
typedef float f32x4 __attribute__((ext_vector_type(4)));

__device__ __forceinline__ float sp_f(float v){ return fmaxf(v,0.f) + log1pf(__expf(-fabsf(v))); }
__device__ __forceinline__ float silu_f(float v){ return v/(1.f+__expf(-v)); }
__device__ __forceinline__ unsigned short f2bf(float f){
  unsigned u = __builtin_bit_cast(unsigned, f);
  unsigned r = (u + 0x7FFFu + ((u>>16)&1u)) >> 16;
  return (unsigned short)r;
}
__device__ __forceinline__ float bf2f(unsigned short us){
  unsigned u = ((unsigned)us)<<16;
  return __builtin_bit_cast(float, u);
}

// ---------------- LayerNorm via LDS transpose (R19-proven) ---------------------------
__global__ __launch_bounds__(256) void ln_kernel(const float* __restrict__ x,
                                                 const float* __restrict__ w,
                                                 const float* __restrict__ bias,
                                                 unsigned short* __restrict__ hb){
  __shared__ float tile[256][33];
  __shared__ float red_s[8][32];
  __shared__ float red_q[8][32];
  __shared__ float mv_mu[32], mv_rs[32];
  int bid = blockIdx.x;            // 256 = b(2) x ltile(128)
  int b = bid >> 7, l0 = (bid & 127)*32;
  int tid = threadIdx.x;
  int cc = tid >> 5, ll = tid & 31;
  const float* xb = x + (size_t)b*DIMC*LSEQ + l0 + ll;
  #pragma unroll 4
  for(int ci=0; ci<32; ci++){
    int c = ci*8 + cc;
    tile[c][ll] = xb[(size_t)c*LSEQ];
  }
  __syncthreads();
  {
    int part = tid >> 5, l = tid & 31;
    float s=0.f, sq=0.f;
    #pragma unroll
    for(int i=0;i<32;i++){ float v = tile[part*32+i][l]; s+=v; sq+=v*v; }
    red_s[part][l]=s; red_q[part][l]=sq;
  }
  __syncthreads();
  if(tid < 32){
    float s=0.f, sq=0.f;
    #pragma unroll
    for(int p=0;p<8;p++){ s+=red_s[p][tid]; sq+=red_q[p][tid]; }
    float mu = s*(1.f/256.f);
    float var = sq*(1.f/256.f) - mu*mu;
    mv_mu[tid]=mu; mv_rs[tid]=rsqrtf(var + 1e-5f);
  }
  __syncthreads();
  int cl = tid & 63, lo = tid >> 6;
  #pragma unroll
  for(int li=0; li<8; li++){
    int l = li*4 + lo;
    float mu = mv_mu[l], rs = mv_rs[l];
    unsigned short* hr = hb + (size_t)(b*4096 + l0 + l)*256;
    #pragma unroll
    for(int c2=0; c2<4; c2++){
      int c = c2*64 + cl;
      hr[c] = f2bf((tile[c][l]-mu)*rs*w[c] + bias[c]);
    }
  }
}

// ---------------- fused weight prep: 5376 blocks, block-range branching --------------
__global__ __launch_bounds__(256) void prep_weights(const float* __restrict__ in_proj_w,
                                                    const float* __restrict__ out_proj_w,
                                                    const float* __restrict__ dtw,
                                                    const float* __restrict__ xpw,
                                                    unsigned short* __restrict__ inw_bf,
                                                    unsigned short* __restrict__ ow_bf,
                                                    unsigned short* __restrict__ wdtx){
  int blk = blockIdx.x, tid = threadIdx.x;
  if(blk < 2048){
    int i = blk*256 + tid;
    inw_bf[i] = f2bf(in_proj_w[i]);
  } else if(blk < 3072){
    int i = (blk-2048)*256 + tid;
    ow_bf[i] = f2bf(out_proj_w[i]);
  } else if(blk < 5120){
    int idx = (blk-3072)*256 + tid;        // 0..524287
    int dep = idx >> 18;
    int r = idx & 262143;
    int n = r >> 9, k = r & 511;
    const float* dw = dtw + (size_t)dep*512*16 + n*16;
    const float* xp = xpw + (size_t)dep*48*512 + k;
    float acc = 0.f;
    #pragma unroll
    for(int j=0;j<16;j++) acc += dw[j] * xp[(size_t)j*512];
    wdtx[(size_t)dep*294912 + r] = f2bf(acc);
  } else if(blk < 5248){
    int i = (blk-5120)*256 + tid;          // 0..32767
    int dep = i >> 14, j = i & 16383;
    wdtx[(size_t)dep*294912 + 262144 + j] = f2bf(xpw[(size_t)dep*48*512 + 16*512 + j]);
  } else {
    int i = (blk-5248)*256 + tid;          // 0..32767
    int dep = i >> 14, j = i & 16383;
    wdtx[(size_t)dep*294912 + 278528 + j] = 0;
  }
}

// ---------------- double-buffered LDS bf16 MFMA GEMM (conv3d_dbuf schedule) ---------
// BM = QM*32, BN = 64, BK = 64; one barrier per K-step; prefetch regs -> ds_write.
template<int QM,int EPI,int WF,int WB>
__global__ __launch_bounds__(256) void gemm_dbuf(
    const unsigned short* __restrict__ A,   // M x K (m rows, B-operand)
    const unsigned short* __restrict__ W,   // N x K (n rows, A-operand)
    const float* __restrict__ bias,
    float* __restrict__ Cf,
    unsigned short* __restrict__ Cb,
    int M, int N, int K){
  __shared__ unsigned short Wt[2][64][72];
  __shared__ unsigned short Xt[2][QM*32][72];
  int tid = threadIdx.x;
  int l = tid & 63, w = tid >> 6;
  int lr = l & 15, lk = l >> 4;
  int w_n = w & 1, w_m = w >> 1;
  int nb = blockIdx.x * 64;
  int mb = blockIdx.y * (QM*32);
  int srow = tid >> 3, sc8 = tid & 7;       // staging: rows 0..31 (+q*32), 16B chunks
  const unsigned short* wr0 = W + (size_t)(nb + srow)*K + sc8*8;
  const unsigned short* wr1 = W + (size_t)(nb + 32 + srow)*K + sc8*8;
  const unsigned short* xr[QM];
  #pragma unroll
  for(int q=0;q<QM;q++) xr[q] = A + (size_t)(mb + q*32 + srow)*K + sc8*8;

  // prologue: stage k0=0 into buf 0
  {
    *(uint4*)&Wt[0][srow   ][sc8*8] = *(const uint4*)(wr0);
    *(uint4*)&Wt[0][srow+32][sc8*8] = *(const uint4*)(wr1);
    #pragma unroll
    for(int q=0;q<QM;q++)
      *(uint4*)&Xt[0][q*32+srow][sc8*8] = *(const uint4*)(xr[q]);
  }
  __syncthreads();

  int nst = K >> 6;
  f32x4 acc[2][QM] = {};
  int cur = 0;
  for(int s=0; s<nst; ++s){
    uint4 wv0, wv1, xv[QM];
    if(s+1 < nst){
      int ko = (s+1)*64;
      wv0 = *(const uint4*)(wr0 + ko);
      wv1 = *(const uint4*)(wr1 + ko);
      #pragma unroll
      for(int q=0;q<QM;q++) xv[q] = *(const uint4*)(xr[q] + ko);
    }
    #pragma unroll
    for(int kk=0;kk<2;kk++){
      short8 af[2], bf[QM];
      #pragma unroll
      for(int i=0;i<2;i++) af[i] = *(const short8*)&Wt[cur][w_n*32+i*16+lr][kk*32+lk*8];
      #pragma unroll
      for(int j=0;j<QM;j++) bf[j] = *(const short8*)&Xt[cur][w_m*(QM*16)+j*16+lr][kk*32+lk*8];
      #pragma unroll
      for(int i=0;i<2;i++)
        #pragma unroll
        for(int j=0;j<QM;j++)
          acc[i][j] = __builtin_amdgcn_mfma_f32_16x16x32_bf16(af[i], bf[j], acc[i][j], 0,0,0);
    }
    if(s+1 < nst){
      int nbuf = cur ^ 1;
      *(uint4*)&Wt[nbuf][srow   ][sc8*8] = wv0;
      *(uint4*)&Wt[nbuf][srow+32][sc8*8] = wv1;
      #pragma unroll
      for(int q=0;q<QM;q++)
        *(uint4*)&Xt[nbuf][q*32+srow][sc8*8] = xv[q];
      __syncthreads();
      cur = nbuf;
    }
  }
  #pragma unroll
  for(int i=0;i<2;i++){
    #pragma unroll
    for(int j=0;j<QM;j++){
      int m = mb + w_m*(QM*16) + j*16 + lr;
      #pragma unroll
      for(int r=0;r<4;r++){
        int n = nb + w_n*32 + i*16 + 4*lk + r;
        float v = acc[i][j][r];
        if(EPI==1) v = sp_f(v + bias[n]);
        if(WF) Cf[(size_t)m*N + n] = v;
        if(WB) Cb[(size_t)m*N + n] = f2bf(v);
      }
    }
  }
}

// ---------------- merged dt + x_proj GEMM, double-buffered (K=512, QM=4) ------------
__global__ __launch_bounds__(256) void gemm_dtx(
    const unsigned short* __restrict__ A,    // u_bf, 8192 x 512
    const unsigned short* __restrict__ W,    // wdtx, 576 x 512
    const float* __restrict__ dtb,
    unsigned short* __restrict__ dtb_out,    // dt_bf
    float* __restrict__ xdbl){
  __shared__ unsigned short Wt[2][64][72];
  __shared__ unsigned short Xt[2][128][72];
  int tid = threadIdx.x;
  int l = tid & 63, w = tid >> 6;
  int lr = l & 15, lk = l >> 4;
  int w_n = w & 1, w_m = w >> 1;
  int nb = blockIdx.x * 64;
  int mb = blockIdx.y * 128;
  int srow = tid >> 3, sc8 = tid & 7;
  const unsigned short* wr0 = W + (size_t)(nb + srow)*512 + sc8*8;
  const unsigned short* wr1 = W + (size_t)(nb + 32 + srow)*512 + sc8*8;
  const unsigned short* xr[4];
  #pragma unroll
  for(int q=0;q<4;q++) xr[q] = A + (size_t)(mb + q*32 + srow)*512 + sc8*8;

  {
    *(uint4*)&Wt[0][srow   ][sc8*8] = *(const uint4*)(wr0);
    *(uint4*)&Wt[0][srow+32][sc8*8] = *(const uint4*)(wr1);
    #pragma unroll
    for(int q=0;q<4;q++)
      *(uint4*)&Xt[0][q*32+srow][sc8*8] = *(const uint4*)(xr[q]);
  }
  __syncthreads();

  f32x4 acc[2][4] = {};
  int cur = 0;
  for(int s=0; s<8; ++s){
    uint4 wv0, wv1, xv[4];
    if(s < 7){
      int ko = (s+1)*64;
      wv0 = *(const uint4*)(wr0 + ko);
      wv1 = *(const uint4*)(wr1 + ko);
      #pragma unroll
      for(int q=0;q<4;q++) xv[q] = *(const uint4*)(xr[q] + ko);
    }
    #pragma unroll
    for(int kk=0;kk<2;kk++){
      short8 af[2], bf[4];
      #pragma unroll
      for(int i=0;i<2;i++) af[i] = *(const short8*)&Wt[cur][w_n*32+i*16+lr][kk*32+lk*8];
      #pragma unroll
      for(int j=0;j<4;j++) bf[j] = *(const short8*)&Xt[cur][w_m*64+j*16+lr][kk*32+lk*8];
      #pragma unroll
      for(int i=0;i<2;i++)
        #pragma unroll
        for(int j=0;j<4;j++)
          acc[i][j] = __builtin_amdgcn_mfma_f32_16x16x32_bf16(af[i], bf[j], acc[i][j], 0,0,0);
    }
    if(s < 7){
      int nbuf = cur ^ 1;
      *(uint4*)&Wt[nbuf][srow   ][sc8*8] = wv0;
      *(uint4*)&Wt[nbuf][srow+32][sc8*8] = wv1;
      #pragma unroll
      for(int q=0;q<4;q++)
        *(uint4*)&Xt[nbuf][q*32+srow][sc8*8] = xv[q];
      __syncthreads();
      cur = nbuf;
    }
  }
  #pragma unroll
  for(int i=0;i<2;i++){
    #pragma unroll
    for(int j=0;j<4;j++){
      int m = mb + w_m*64 + j*16 + lr;
      #pragma unroll
      for(int r=0;r<4;r++){
        int n = nb + w_n*32 + i*16 + 4*lk + r;
        float v = acc[i][j][r];
        if(n < 512){
          dtb_out[(size_t)m*512 + n] = f2bf(sp_f(v + dtb[n]));
        } else if(n < 544){
          xdbl[(size_t)m*32 + (n-512)] = v;
        }
      }
    }
  }
}

// ---------------- causal depthwise conv1d (k=4) + bias + SiLU (xz bf16) -> u_bf -----
__global__ __launch_bounds__(256) void conv1d_silu_kernel(const unsigned short* __restrict__ xz,
                                                          const float* __restrict__ cw,
                                                          const float* __restrict__ cb,
                                                          unsigned short* __restrict__ ub){
  int g = blockIdx.x*256 + threadIdx.x;   // b*2^21 + l*512 + d
  int d = g & 511;
  int l = (g>>9) & 4095;
  int b = g >> 21;
  const unsigned short* up = xz + (size_t)b*LSEQ*1024 + d;
  float accv = cb[d];
  #pragma unroll
  for(int k=0;k<4;k++){
    int ls = l-3+k;
    float vv = (ls>=0) ? bf2f(up[(size_t)ls*1024]) : 0.f;
    accv += vv * cw[d*4+k];
  }
  ub[(size_t)g] = f2bf(silu_f(accv));
}

// ================= chunked selective scan, 16 states in registers (R16-proven) ======
__global__ __launch_bounds__(256) void scan_pass1(const unsigned short* __restrict__ dt,
                                                  const unsigned short* __restrict__ u,
                                                  const float* __restrict__ xdbl,
                                                  const float* __restrict__ A_log,
                                                  float* __restrict__ Ap,
                                                  float* __restrict__ Ep){
  __shared__ float bc[CHL*32];
  int bid = blockIdx.x;            // 512 = b(2) x ch(128) x dh(2)
  int b = bid >> 8, ch = (bid >> 1) & 127, dh = bid & 1;
  int tid = threadIdx.x;
  int d = dh*256 + tid;
  int row0 = b*4096 + ch*CHL;
  *(float4*)&bc[tid*4] = *(const float4*)&xdbl[(size_t)row0*32 + tid*4];
  __syncthreads();
  float a[16];
  #pragma unroll
  for(int s=0;s<16;s++) a[s] = -__expf(A_log[d*16+s]);
  float h[16];
  #pragma unroll
  for(int s=0;s<16;s++) h[s] = 0.f;
  float sumdt = 0.f;
  const unsigned short* dtp = dt + (size_t)row0*512 + d;
  const unsigned short* up  = u  + (size_t)row0*512 + d;
  for(int t=0;t<CHL;t++){
    float dtv = bf2f(dtp[(size_t)t*512]);
    float uv  = bf2f(up[(size_t)t*512]);
    float dtbu = dtv*uv;
    sumdt += dtv;
    #pragma unroll
    for(int s=0;s<16;s++){
      float dA = __expf(a[s]*dtv);
      h[s] = dA*h[s] + dtbu*bc[t*32+s];
    }
  }
  int bd = b*512 + d;
  #pragma unroll
  for(int s=0;s<16;s++){
    Ap[(size_t)ch*16384 + s*1024 + bd] = __expf(a[s]*sumdt);
    Ep[(size_t)ch*16384 + s*1024 + bd] = h[s];
  }
}

// exclusive scan over chunks; unroll-4 with batched loads for latency overlap
__global__ __launch_bounds__(256) void scan_pass2(const float* __restrict__ Ap,
                                                  float* __restrict__ Ep){
  int idx = blockIdx.x*256 + threadIdx.x;   // 0..16383
  float h = 0.f;
  for(int c=0;c<NCH;c+=4){
    float a0 = Ap[(size_t)(c+0)*16384 + idx];
    float a1 = Ap[(size_t)(c+1)*16384 + idx];
    float a2 = Ap[(size_t)(c+2)*16384 + idx];
    float a3 = Ap[(size_t)(c+3)*16384 + idx];
    float e0 = Ep[(size_t)(c+0)*16384 + idx];
    float e1 = Ep[(size_t)(c+1)*16384 + idx];
    float e2 = Ep[(size_t)(c+2)*16384 + idx];
    float e3 = Ep[(size_t)(c+3)*16384 + idx];
    Ep[(size_t)(c+0)*16384 + idx] = h; h = a0*h + e0;
    Ep[(size_t)(c+1)*16384 + idx] = h; h = a1*h + e1;
    Ep[(size_t)(c+2)*16384 + idx] = h; h = a2*h + e2;
    Ep[(size_t)(c+3)*16384 + idx] = h; h = a3*h + e3;
  }
}

__global__ __launch_bounds__(256) void scan_pass3(const unsigned short* __restrict__ dt,
                                                  const unsigned short* __restrict__ u,
                                                  const unsigned short* __restrict__ xz,
                                                  const float* __restrict__ xdbl,
                                                  const float* __restrict__ A_log,
                                                  const float* __restrict__ Ep,
                                                  const float* __restrict__ Dsk,
                                                  unsigned short* __restrict__ yb){
  __shared__ float bc[CHL*32];
  int bid = blockIdx.x;            // 512 = b(2) x ch(128) x dh(2)
  int b = bid >> 8, ch = (bid >> 1) & 127, dh = bid & 1;
  int tid = threadIdx.x;
  int d = dh*256 + tid;
  int row0 = b*4096 + ch*CHL;
  *(float4*)&bc[tid*4] = *(const float4*)&xdbl[(size_t)row0*32 + tid*4];
  __syncthreads();
  float a[16];
  #pragma unroll
  for(int s=0;s<16;s++) a[s] = -__expf(A_log[d*16+s]);
  int bd = b*512 + d;
  float h[16];
  #pragma unroll
  for(int s=0;s<16;s++) h[s] = Ep[(size_t)ch*16384 + s*1024 + bd];
  float dskv = Dsk[d];
  const unsigned short* dtp = dt + (size_t)row0*512 + d;
  const unsigned short* up  = u  + (size_t)row0*512 + d;
  const unsigned short* zp  = xz + (size_t)row0*1024 + 512 + d;
  unsigned short* yp = yb + (size_t)row0*512 + d;
  for(int t=0;t<CHL;t++){
    float dtv = bf2f(dtp[(size_t)t*512]);
    float uv  = bf2f(up[(size_t)t*512]);
    float dtbu = dtv*uv;
    float y = 0.f;
    #pragma unroll
    for(int s=0;s<16;s++){
      float dA = __expf(a[s]*dtv);
      h[s] = dA*h[s] + dtbu*bc[t*32+s];
      y += h[s]*bc[t*32+16+s];
    }
    float z = bf2f(zp[(size_t)t*1024]);
    yp[(size_t)t*512] = f2bf((y + uv*dskv) * silu_f(z));
  }
}

// ================= conv3d prep: fused xt_fill + wt_conv (7560 blocks) ===============
__global__ __launch_bounds__(256) void conv_prep(const float* __restrict__ x,
                                                 const float* __restrict__ w3,
                                                 unsigned short* __restrict__ xt,
                                                 unsigned short* __restrict__ wt){
  int blk = blockIdx.x, t = threadIdx.x;
  if(blk < 648){
    int b = blk / 324; int r = blk - b*324;
    int zz = r / 18, yy = r - zz*18;
    bool inner = (zz>=1 && zz<=16 && yy>=1 && yy<=16);
    unsigned short* xd = xt + (size_t)((b*18 + zz)*18 + yy)*18*256;
    const float* xs = x + (size_t)b*256*4096 + (zz-1)*256 + (yy-1)*16;
    for(int u = t; u < 576; u += 256){
      int xpos = u >> 5;           // 0..17
      int ci0 = (u & 31) * 8;
      uint4 val = make_uint4(0,0,0,0);
      if(inner && xpos>=1 && xpos<=16){
        int xi = xpos-1;
        unsigned pk[4];
        #pragma unroll
        for(int j=0;j<4;j++){
          unsigned short lo = f2bf(xs[(size_t)(ci0+2*j  )*4096 + xi]);
          unsigned short hi = f2bf(xs[(size_t)(ci0+2*j+1)*4096 + xi]);
          pk[j] = (unsigned)lo | ((unsigned)hi << 16);
        }
        val = make_uint4(pk[0],pk[1],pk[2],pk[3]);
      }
      *(uint4*)(xd + (size_t)u*8) = val;
    }
  } else {
    int idx = (blk-648)*256 + t;   // 0..1,769,471
    int ci = idx & 255; int r = idx >> 8;
    int tap = r % 27, co = r / 27;
    wt[idx] = f2bf(w3[(size_t)co*6912 + ci*27 + tap]);
  }
}

// conv3d: BK=128 double-buffered LDS MFMA implicit GEMM (R16-proven, 62 us).
__global__ __launch_bounds__(512) void conv3d_dbuf(const unsigned short* __restrict__ xt,
                                                   const unsigned short* __restrict__ wt,
                                                   const unsigned short* __restrict__ hb,
                                                   const float* __restrict__ prelu_a,
                                                   const float* __restrict__ scale,
                                                   float* __restrict__ out){
  __shared__ unsigned short Wt2[2][64][136];
  __shared__ unsigned short Xt2[2][128][136];
  int bid0 = blockIdx.x;
  int bid = (bid0 & 7)*32 + (bid0 >> 3);    // bijective XCD swizzle
  int nb = (bid & 3)*64;                    // co tile
  int mb = (bid >> 2)*128;                  // m tile
  int tid = threadIdx.x;
  int l = tid & 63, w = tid >> 6;
  int lr = l & 15, lk = l >> 4;
  int w_n = w & 1, w_m = w >> 1;            // 2 x 4
  int srow = tid >> 4, sch = tid & 15;      // staging: row-base 0..31, 16B chunk 0..15
  size_t xbase[4];
  #pragma unroll
  for(int q=0;q<4;q++){
    int m = mb + q*32 + srow;
    int b = m >> 12, sp = m & 4095;
    int z = sp >> 8, y = (sp >> 4) & 15, x = sp & 15;
    xbase[q] = (size_t)(((b*18 + z+1)*18 + (y+1))*18 + (x+1))*256 + sch*8;
  }
  const unsigned short* wrow0 = wt + (size_t)(nb + srow)*6912 + sch*8;
  const unsigned short* wrow1 = wt + (size_t)(nb + 32 + srow)*6912 + sch*8;

  {
    int toff = (-324 - 18 - 1)*256;
    uint4 w0 = *(const uint4*)(wrow0);
    uint4 w1 = *(const uint4*)(wrow1);
    uint4 x0 = *(const uint4*)(xt + xbase[0] + toff);
    uint4 x1 = *(const uint4*)(xt + xbase[1] + toff);
    uint4 x2 = *(const uint4*)(xt + xbase[2] + toff);
    uint4 x3 = *(const uint4*)(xt + xbase[3] + toff);
    *(uint4*)&Wt2[0][srow   ][sch*8] = w0;
    *(uint4*)&Wt2[0][srow+32][sch*8] = w1;
    *(uint4*)&Xt2[0][srow    ][sch*8] = x0;
    *(uint4*)&Xt2[0][srow+32 ][sch*8] = x1;
    *(uint4*)&Xt2[0][srow+64 ][sch*8] = x2;
    *(uint4*)&Xt2[0][srow+96 ][sch*8] = x3;
  }
  __syncthreads();

  f32x4 acc[2][2] = {};
  int cur = 0;
  for(int s=0; s<54; ++s){
    uint4 wv0, wv1, xv0, xv1, xv2, xv3;
    if(s < 53){
      int sn = s+1;
      int tap = sn >> 1, h = sn & 1;
      int gz = tap/9; int rm = tap - gz*9; int gy = rm/3, gx = rm - gy*3;
      int toff = ((gz-1)*324 + (gy-1)*18 + (gx-1))*256 + h*128;
      int kco = tap*256 + h*128;
      wv0 = *(const uint4*)(wrow0 + kco);
      wv1 = *(const uint4*)(wrow1 + kco);
      xv0 = *(const uint4*)(xt + xbase[0] + toff);
      xv1 = *(const uint4*)(xt + xbase[1] + toff);
      xv2 = *(const uint4*)(xt + xbase[2] + toff);
      xv3 = *(const uint4*)(xt + xbase[3] + toff);
    }
    #pragma unroll
    for(int kk=0;kk<4;kk++){
      short8 af[2], bf[2];
      #pragma unroll
      for(int i=0;i<2;i++) af[i] = *(const short8*)&Wt2[cur][w_n*32+i*16+lr][kk*32+lk*8];
      #pragma unroll
      for(int j=0;j<2;j++) bf[j] = *(const short8*)&Xt2[cur][w_m*32+j*16+lr][kk*32+lk*8];
      #pragma unroll
      for(int i=0;i<2;i++)
        #pragma unroll
        for(int j=0;j<2;j++)
          acc[i][j] = __builtin_amdgcn_mfma_f32_16x16x32_bf16(af[i], bf[j], acc[i][j], 0,0,0);
    }
    if(s < 53){
      int nbuf = cur ^ 1;
      *(uint4*)&Wt2[nbuf][srow   ][sch*8] = wv0;
      *(uint4*)&Wt2[nbuf][srow+32][sch*8] = wv1;
      *(uint4*)&Xt2[nbuf][srow    ][sch*8] = xv0;
      *(uint4*)&Xt2[nbuf][srow+32 ][sch*8] = xv1;
      *(uint4*)&Xt2[nbuf][srow+64 ][sch*8] = xv2;
      *(uint4*)&Xt2[nbuf][srow+96 ][sch*8] = xv3;
      __syncthreads();
      cur = nbuf;
    }
  }

  float spv = sp_f(scale[0]);
  float pa = prelu_a[0];
  #pragma unroll
  for(int i=0;i<2;i++){
    #pragma unroll
    for(int j=0;j<2;j++){
      int m = mb + w_m*32 + j*16 + lr;
      int bb = m >> 12, sp = m & 4095;
      #pragma unroll
      for(int r=0;r<4;r++){
        int co = nb + w_n*32 + i*16 + 4*lk + r;
        float cval = acc[i][j][r];
        float pr = cval > 0.f ? cval : pa*cval;
        out[((size_t)(bb*256 + co))*4096 + sp] = bf2f(hb[(size_t)m*256 + co]) + spv*pr;
      }
    }
  }
}

extern "C" void kernel_launch(void* const* d_in, const int* in_sizes, int n_in,
                              void* d_out, int out_size, void* d_ws, size_t ws_size,
                              hipStream_t stream) {
  const float* x         = (const float*)d_in[0];
  const float* ln_w      = (const float*)d_in[1];
  const float* ln_b      = (const float*)d_in[2];
  const float* in_proj_w = (const float*)d_in[3];
  const float* conv_w    = (const float*)d_in[4];
  const float* conv_b    = (const float*)d_in[5];
  const float* x_proj_w  = (const float*)d_in[6];
  const float* dt_proj_w = (const float*)d_in[7];
  const float* dt_proj_b = (const float*)d_in[8];
  const float* A_log     = (const float*)d_in[9];
  const float* D_skip    = (const float*)d_in[10];
  const float* out_proj_w= (const float*)d_in[11];
  const float* conv3d_w  = (const float*)d_in[12];
  const float* prelu_a   = (const float*)d_in[13];
  const float* scale     = (const float*)d_in[14];
  float* out = (float*)d_out;

  // workspace layout (float offsets) — one producer per phase (R19-proven).
  float* ws   = (float*)d_ws;
  float* Ap   = ws;                               // 2,097,152 fl
  float* Ep   = Ap + 2097152;                     // 2,097,152 fl
  unsigned short* xz_bf = (unsigned short*)(Ep + 2097152);     // 8,388,608 bf16
  unsigned short* u_bf  = xz_bf + 8388608;        // 4,194,304 bf16
  float* xdbl = (float*)(u_bf + 4194304);         // 262,144 fl
  unsigned short* dt_bf = (unsigned short*)(xdbl + 262144);    // 4,194,304 bf16
  unsigned short* h_bf  = dt_bf + 4194304;        // 2,097,152 bf16 (LIVE at conv time)
  unsigned short* y_bf  = h_bf + 2097152;         // 4,194,304 bf16
  unsigned short* inw_bf   = y_bf + 4194304;      // 524,288 bf16
  unsigned short* ow_bf    = inw_bf + 524288;     // 262,144 bf16
  unsigned short* wdtx_bf  = ow_bf + 262144;      // 589,824 bf16 (2 x 576 x 512)
  const size_t base_floats = 16678912;            // 66,715,648 bytes
  // xt/wt tail: end = 76,226,560 B <= 77,070,336 B (proven)
  unsigned short* xt = (unsigned short*)(ws + base_floats);
  unsigned short* wt = xt + 2985984;

  // ---- fused weight prep ----
  prep_weights<<<5376, 256, 0, stream>>>(in_proj_w, out_proj_w, dt_proj_w, x_proj_w,
                                         inw_bf, ow_bf, wdtx_bf);

  ln_kernel<<<256, 256, 0, stream>>>(x, ln_w, ln_b, h_bf);

  for(int dep=0; dep<2; dep++){
    const unsigned short* inw  = inw_bf  + (size_t)dep*262144;
    const unsigned short* oww  = ow_bf   + (size_t)dep*131072;
    const unsigned short* wdtx = wdtx_bf + (size_t)dep*294912;
    const float* cw   = conv_w    + (size_t)dep*512*4;
    const float* cb   = conv_b    + (size_t)dep*512;
    const float* dtb  = dt_proj_b + (size_t)dep*512;
    const float* Alg  = A_log     + (size_t)dep*512*16;
    const float* Dsk  = D_skip    + (size_t)dep*512;

    // in_proj: xz_bf[8192,1024] = h_bf @ inw^T   (16 x 64 = 1024 blocks, dbuf)
    gemm_dbuf<4,0,0,1><<<dim3(16,64), 256, 0, stream>>>(
        h_bf, inw, nullptr, nullptr, xz_bf, 8192, 1024, 256);
    conv1d_silu_kernel<<<16384, 256, 0, stream>>>(xz_bf, cw, cb, u_bf);
    // merged dt + x_proj: dt_bf + xdbl from one pass over u  (9 x 64 = 576 blocks, dbuf)
    gemm_dtx<<<dim3(9,64), 256, 0, stream>>>(u_bf, wdtx, dtb, dt_bf, xdbl);

    scan_pass1<<<512, 256, 0, stream>>>(dt_bf, u_bf, xdbl, Alg, Ap, Ep);
    scan_pass2<<<64, 256, 0, stream>>>(Ap, Ep);
    scan_pass3<<<512, 256, 0, stream>>>(dt_bf, u_bf, xz_bf, xdbl, Alg, Ep, Dsk, y_bf);

    // out_proj: h_bf[8192,256] = y_bf @ ow^T  (BM=64: 4 x 128 = 512 blocks, dbuf)
    gemm_dbuf<2,0,0,1><<<dim3(4,128), 256, 0, stream>>>(
        y_bf, oww, nullptr, nullptr, h_bf, 8192, 256, 512);
  }

  // conv3d: fused prep + BK=128 double-buffered MFMA conv with fused epilogue
  conv_prep<<<7560, 256, 0, stream>>>(x, conv3d_w, xt, wt);
  conv3d_dbuf<<<256, 512, 0, stream>>>(xt, wt, h_bf, prelu_a, scale, out);
}

// Round 23
// 373.308 us; speedup vs baseline: 1.1850x; 1.1850x over previous
//
#include <hip/hip_runtime.h>
#include <math.h>

#define LSEQ 4096
#define DIMC 256
#define DI   512
#define NCH  128    // chunks over L
#define CHL  32     // chunk length

typedef short short8 __attribute__((ext_vector_type(8)));
typedef float f32x4 __attribute__((ext_vector_type(4)));

__device__ __forceinline__ float sp_f(float v){ return fmaxf(v,0.f) + log1pf(__expf(-fabsf(v))); }
__device__ __forceinline__ float silu_f(float v){ return v/(1.f+__expf(-v)); }
__device__ __forceinline__ unsigned short f2bf(float f){
  unsigned u = __builtin_bit_cast(unsigned, f);
  unsigned r = (u + 0x7FFFu + ((u>>16)&1u)) >> 16;
  return (unsigned short)r;
}
__device__ __forceinline__ float bf2f(unsigned short us){
  unsigned u = ((unsigned)us)<<16;
  return __builtin_bit_cast(float, u);
}

// ---------------- LayerNorm via LDS transpose (R19-proven) ---------------------------
__global__ __launch_bounds__(256) void ln_kernel(const float* __restrict__ x,
                                                 const float* __restrict__ w,
                                                 const float* __restrict__ bias,
                                                 unsigned short* __restrict__ hb){
  __shared__ float tile[256][33];
  __shared__ float red_s[8][32];
  __shared__ float red_q[8][32];
  __shared__ float mv_mu[32], mv_rs[32];
  int bid = blockIdx.x;            // 256 = b(2) x ltile(128)
  int b = bid >> 7, l0 = (bid & 127)*32;
  int tid = threadIdx.x;
  int cc = tid >> 5, ll = tid & 31;
  const float* xb = x + (size_t)b*DIMC*LSEQ + l0 + ll;
  #pragma unroll 4
  for(int ci=0; ci<32; ci++){
    int c = ci*8 + cc;
    tile[c][ll] = xb[(size_t)c*LSEQ];
  }
  __syncthreads();
  {
    int part = tid >> 5, l = tid & 31;
    float s=0.f, sq=0.f;
    #pragma unroll
    for(int i=0;i<32;i++){ float v = tile[part*32+i][l]; s+=v; sq+=v*v; }
    red_s[part][l]=s; red_q[part][l]=sq;
  }
  __syncthreads();
  if(tid < 32){
    float s=0.f, sq=0.f;
    #pragma unroll
    for(int p=0;p<8;p++){ s+=red_s[p][tid]; sq+=red_q[p][tid]; }
    float mu = s*(1.f/256.f);
    float var = sq*(1.f/256.f) - mu*mu;
    mv_mu[tid]=mu; mv_rs[tid]=rsqrtf(var + 1e-5f);
  }
  __syncthreads();
  int cl = tid & 63, lo = tid >> 6;
  #pragma unroll
  for(int li=0; li<8; li++){
    int l = li*4 + lo;
    float mu = mv_mu[l], rs = mv_rs[l];
    unsigned short* hr = hb + (size_t)(b*4096 + l0 + l)*256;
    #pragma unroll
    for(int c2=0; c2<4; c2++){
      int c = c2*64 + cl;
      hr[c] = f2bf((tile[c][l]-mu)*rs*w[c] + bias[c]);
    }
  }
}

// ---------------- fused weight prep: 5376 blocks, block-range branching --------------
__global__ __launch_bounds__(256) void prep_weights(const float* __restrict__ in_proj_w,
                                                    const float* __restrict__ out_proj_w,
                                                    const float* __restrict__ dtw,
                                                    const float* __restrict__ xpw,
                                                    unsigned short* __restrict__ inw_bf,
                                                    unsigned short* __restrict__ ow_bf,
                                                    unsigned short* __restrict__ wdtx){
  int blk = blockIdx.x, tid = threadIdx.x;
  if(blk < 2048){
    int i = blk*256 + tid;
    inw_bf[i] = f2bf(in_proj_w[i]);
  } else if(blk < 3072){
    int i = (blk-2048)*256 + tid;
    ow_bf[i] = f2bf(out_proj_w[i]);
  } else if(blk < 5120){
    int idx = (blk-3072)*256 + tid;        // 0..524287
    int dep = idx >> 18;
    int r = idx & 262143;
    int n = r >> 9, k = r & 511;
    const float* dw = dtw + (size_t)dep*512*16 + n*16;
    const float* xp = xpw + (size_t)dep*48*512 + k;
    float acc = 0.f;
    #pragma unroll
    for(int j=0;j<16;j++) acc += dw[j] * xp[(size_t)j*512];
    wdtx[(size_t)dep*294912 + r] = f2bf(acc);
  } else if(blk < 5248){
    int i = (blk-5120)*256 + tid;          // 0..32767
    int dep = i >> 14, j = i & 16383;
    wdtx[(size_t)dep*294912 + 262144 + j] = f2bf(xpw[(size_t)dep*48*512 + 16*512 + j]);
  } else {
    int i = (blk-5248)*256 + tid;          // 0..32767
    int dep = i >> 14, j = i & 16383;
    wdtx[(size_t)dep*294912 + 278528 + j] = 0;
  }
}

// ---------------- LDS-staged bf16 MFMA GEMM, BM = QM*32 (R14-proven structure) ------
template<int QM,int EPI,int WF,int WB>
__global__ __launch_bounds__(256) void gemm_lds(
    const unsigned short* __restrict__ A,   // M x K (m rows, B-operand)
    const unsigned short* __restrict__ W,   // N x K (n rows, A-operand)
    const float* __restrict__ bias,
    float* __restrict__ Cf,
    unsigned short* __restrict__ Cb,
    int M, int N, int K){
  __shared__ unsigned short Wt[64][72];
  __shared__ unsigned short Xt[QM*32][72];
  int tid = threadIdx.x;
  int l = tid & 63, w = tid >> 6;
  int lr = l & 15, lk = l >> 4;
  int w_n = w & 1, w_m = w >> 1;
  int nb = blockIdx.x * 64;
  int mb = blockIdx.y * (QM*32);
  int srow = tid >> 3, sc8 = tid & 7;       // staging: 8 threads/row, 16B each
  f32x4 acc[2][QM] = {};
  for(int k0 = 0; k0 < K; k0 += 64){
    __syncthreads();
    #pragma unroll
    for(int q=0;q<2;q++){
      int row = q*32 + srow;
      *(uint4*)&Wt[row][sc8*8] = *(const uint4*)(W + (size_t)(nb+row)*K + k0 + sc8*8);
    }
    #pragma unroll
    for(int q=0;q<QM;q++){
      int row = q*32 + srow;
      *(uint4*)&Xt[row][sc8*8] = *(const uint4*)(A + (size_t)(mb+row)*K + k0 + sc8*8);
    }
    __syncthreads();
    #pragma unroll
    for(int kk=0;kk<2;kk++){
      short8 af[2], bf[QM];
      #pragma unroll
      for(int i=0;i<2;i++) af[i] = *(const short8*)&Wt[w_n*32+i*16+lr][kk*32+lk*8];
      #pragma unroll
      for(int j=0;j<QM;j++) bf[j] = *(const short8*)&Xt[w_m*(QM*16)+j*16+lr][kk*32+lk*8];
      #pragma unroll
      for(int i=0;i<2;i++)
        #pragma unroll
        for(int j=0;j<QM;j++)
          acc[i][j] = __builtin_amdgcn_mfma_f32_16x16x32_bf16(af[i], bf[j], acc[i][j], 0,0,0);
    }
  }
  #pragma unroll
  for(int i=0;i<2;i++){
    #pragma unroll
    for(int j=0;j<QM;j++){
      int m = mb + w_m*(QM*16) + j*16 + lr;
      #pragma unroll
      for(int r=0;r<4;r++){
        int n = nb + w_n*32 + i*16 + 4*lk + r;
        float v = acc[i][j][r];
        if(EPI==1) v = sp_f(v + bias[n]);
        if(WF) Cf[(size_t)m*N + n] = v;
        if(WB) Cb[(size_t)m*N + n] = f2bf(v);
      }
    }
  }
}

// ---------------- merged dt + x_proj GEMM over wdtx[576][512] (R19-proven) ----------
__global__ __launch_bounds__(256) void gemm_dtx(
    const unsigned short* __restrict__ A,    // u_bf, 8192 x 512
    const unsigned short* __restrict__ W,    // wdtx, 576 x 512
    const float* __restrict__ dtb,
    unsigned short* __restrict__ dtb_out,    // dt_bf
    float* __restrict__ xdbl){
  __shared__ unsigned short Wt[64][72];
  __shared__ unsigned short Xt[128][72];
  int tid = threadIdx.x;
  int l = tid & 63, w = tid >> 6;
  int lr = l & 15, lk = l >> 4;
  int w_n = w & 1, w_m = w >> 1;
  int nb = blockIdx.x * 64;
  int mb = blockIdx.y * 128;
  int srow = tid >> 3, sc8 = tid & 7;
  f32x4 acc[2][4] = {};
  for(int k0 = 0; k0 < 512; k0 += 64){
    __syncthreads();
    #pragma unroll
    for(int q=0;q<2;q++){
      int row = q*32 + srow;
      *(uint4*)&Wt[row][sc8*8] = *(const uint4*)(W + (size_t)(nb+row)*512 + k0 + sc8*8);
    }
    #pragma unroll
    for(int q=0;q<4;q++){
      int row = q*32 + srow;
      *(uint4*)&Xt[row][sc8*8] = *(const uint4*)(A + (size_t)(mb+row)*512 + k0 + sc8*8);
    }
    __syncthreads();
    #pragma unroll
    for(int kk=0;kk<2;kk++){
      short8 af[2], bf[4];
      #pragma unroll
      for(int i=0;i<2;i++) af[i] = *(const short8*)&Wt[w_n*32+i*16+lr][kk*32+lk*8];
      #pragma unroll
      for(int j=0;j<4;j++) bf[j] = *(const short8*)&Xt[w_m*64+j*16+lr][kk*32+lk*8];
      #pragma unroll
      for(int i=0;i<2;i++)
        #pragma unroll
        for(int j=0;j<4;j++)
          acc[i][j] = __builtin_amdgcn_mfma_f32_16x16x32_bf16(af[i], bf[j], acc[i][j], 0,0,0);
    }
  }
  #pragma unroll
  for(int i=0;i<2;i++){
    #pragma unroll
    for(int j=0;j<4;j++){
      int m = mb + w_m*64 + j*16 + lr;
      #pragma unroll
      for(int r=0;r<4;r++){
        int n = nb + w_n*32 + i*16 + 4*lk + r;
        float v = acc[i][j][r];
        if(n < 512){
          dtb_out[(size_t)m*512 + n] = f2bf(sp_f(v + dtb[n]));
        } else if(n < 544){
          xdbl[(size_t)m*32 + (n-512)] = v;
        }
      }
    }
  }
}

// ---------------- causal depthwise conv1d (k=4) + bias + SiLU (xz bf16) -> u_bf -----
__global__ __launch_bounds__(256) void conv1d_silu_kernel(const unsigned short* __restrict__ xz,
                                                          const float* __restrict__ cw,
                                                          const float* __restrict__ cb,
                                                          unsigned short* __restrict__ ub){
  int g = blockIdx.x*256 + threadIdx.x;   // b*2^21 + l*512 + d
  int d = g & 511;
  int l = (g>>9) & 4095;
  int b = g >> 21;
  const unsigned short* up = xz + (size_t)b*LSEQ*1024 + d;
  float accv = cb[d];
  #pragma unroll
  for(int k=0;k<4;k++){
    int ls = l-3+k;
    float vv = (ls>=0) ? bf2f(up[(size_t)ls*1024]) : 0.f;
    accv += vv * cw[d*4+k];
  }
  ub[(size_t)g] = f2bf(silu_f(accv));
}

// ================= chunked selective scan, 16 states in registers (R16-proven) ======
__global__ __launch_bounds__(256) void scan_pass1(const unsigned short* __restrict__ dt,
                                                  const unsigned short* __restrict__ u,
                                                  const float* __restrict__ xdbl,
                                                  const float* __restrict__ A_log,
                                                  float* __restrict__ Ap,
                                                  float* __restrict__ Ep){
  __shared__ float bc[CHL*32];
  int bid = blockIdx.x;            // 512 = b(2) x ch(128) x dh(2)
  int b = bid >> 8, ch = (bid >> 1) & 127, dh = bid & 1;
  int tid = threadIdx.x;
  int d = dh*256 + tid;
  int row0 = b*4096 + ch*CHL;
  *(float4*)&bc[tid*4] = *(const float4*)&xdbl[(size_t)row0*32 + tid*4];
  __syncthreads();
  float a[16];
  #pragma unroll
  for(int s=0;s<16;s++) a[s] = -__expf(A_log[d*16+s]);
  float h[16];
  #pragma unroll
  for(int s=0;s<16;s++) h[s] = 0.f;
  float sumdt = 0.f;
  const unsigned short* dtp = dt + (size_t)row0*512 + d;
  const unsigned short* up  = u  + (size_t)row0*512 + d;
  for(int t=0;t<CHL;t++){
    float dtv = bf2f(dtp[(size_t)t*512]);
    float uv  = bf2f(up[(size_t)t*512]);
    float dtbu = dtv*uv;
    sumdt += dtv;
    #pragma unroll
    for(int s=0;s<16;s++){
      float dA = __expf(a[s]*dtv);
      h[s] = dA*h[s] + dtbu*bc[t*32+s];
    }
  }
  int bd = b*512 + d;
  #pragma unroll
  for(int s=0;s<16;s++){
    Ap[(size_t)ch*16384 + s*1024 + bd] = __expf(a[s]*sumdt);
    Ep[(size_t)ch*16384 + s*1024 + bd] = h[s];
  }
}

// exclusive scan over chunks; unroll-4 with batched loads for latency overlap
__global__ __launch_bounds__(256) void scan_pass2(const float* __restrict__ Ap,
                                                  float* __restrict__ Ep){
  int idx = blockIdx.x*256 + threadIdx.x;   // 0..16383
  float h = 0.f;
  for(int c=0;c<NCH;c+=4){
    float a0 = Ap[(size_t)(c+0)*16384 + idx];
    float a1 = Ap[(size_t)(c+1)*16384 + idx];
    float a2 = Ap[(size_t)(c+2)*16384 + idx];
    float a3 = Ap[(size_t)(c+3)*16384 + idx];
    float e0 = Ep[(size_t)(c+0)*16384 + idx];
    float e1 = Ep[(size_t)(c+1)*16384 + idx];
    float e2 = Ep[(size_t)(c+2)*16384 + idx];
    float e3 = Ep[(size_t)(c+3)*16384 + idx];
    Ep[(size_t)(c+0)*16384 + idx] = h; h = a0*h + e0;
    Ep[(size_t)(c+1)*16384 + idx] = h; h = a1*h + e1;
    Ep[(size_t)(c+2)*16384 + idx] = h; h = a2*h + e2;
    Ep[(size_t)(c+3)*16384 + idx] = h; h = a3*h + e3;
  }
}

__global__ __launch_bounds__(256) void scan_pass3(const unsigned short* __restrict__ dt,
                                                  const unsigned short* __restrict__ u,
                                                  const unsigned short* __restrict__ xz,
                                                  const float* __restrict__ xdbl,
                                                  const float* __restrict__ A_log,
                                                  const float* __restrict__ Ep,
                                                  const float* __restrict__ Dsk,
                                                  unsigned short* __restrict__ yb){
  __shared__ float bc[CHL*32];
  int bid = blockIdx.x;            // 512 = b(2) x ch(128) x dh(2)
  int b = bid >> 8, ch = (bid >> 1) & 127, dh = bid & 1;
  int tid = threadIdx.x;
  int d = dh*256 + tid;
  int row0 = b*4096 + ch*CHL;
  *(float4*)&bc[tid*4] = *(const float4*)&xdbl[(size_t)row0*32 + tid*4];
  __syncthreads();
  float a[16];
  #pragma unroll
  for(int s=0;s<16;s++) a[s] = -__expf(A_log[d*16+s]);
  int bd = b*512 + d;
  float h[16];
  #pragma unroll
  for(int s=0;s<16;s++) h[s] = Ep[(size_t)ch*16384 + s*1024 + bd];
  float dskv = Dsk[d];
  const unsigned short* dtp = dt + (size_t)row0*512 + d;
  const unsigned short* up  = u  + (size_t)row0*512 + d;
  const unsigned short* zp  = xz + (size_t)row0*1024 + 512 + d;
  unsigned short* yp = yb + (size_t)row0*512 + d;
  for(int t=0;t<CHL;t++){
    float dtv = bf2f(dtp[(size_t)t*512]);
    float uv  = bf2f(up[(size_t)t*512]);
    float dtbu = dtv*uv;
    float y = 0.f;
    #pragma unroll
    for(int s=0;s<16;s++){
      float dA = __expf(a[s]*dtv);
      h[s] = dA*h[s] + dtbu*bc[t*32+s];
      y += h[s]*bc[t*32+16+s];
    }
    float z = bf2f(zp[(size_t)t*1024]);
    yp[(size_t)t*512] = f2bf((y + uv*dskv) * silu_f(z));
  }
}

// ================= conv3d prep: fused xt_fill + wt_conv (7560 blocks) ===============
__global__ __launch_bounds__(256) void conv_prep(const float* __restrict__ x,
                                                 const float* __restrict__ w3,
                                                 unsigned short* __restrict__ xt,
                                                 unsigned short* __restrict__ wt){
  int blk = blockIdx.x, t = threadIdx.x;
  if(blk < 648){
    int b = blk / 324; int r = blk - b*324;
    int zz = r / 18, yy = r - zz*18;
    bool inner = (zz>=1 && zz<=16 && yy>=1 && yy<=16);
    unsigned short* xd = xt + (size_t)((b*18 + zz)*18 + yy)*18*256;
    const float* xs = x + (size_t)b*256*4096 + (zz-1)*256 + (yy-1)*16;
    for(int u = t; u < 576; u += 256){
      int xpos = u >> 5;           // 0..17
      int ci0 = (u & 31) * 8;
      uint4 val = make_uint4(0,0,0,0);
      if(inner && xpos>=1 && xpos<=16){
        int xi = xpos-1;
        unsigned pk[4];
        #pragma unroll
        for(int j=0;j<4;j++){
          unsigned short lo = f2bf(xs[(size_t)(ci0+2*j  )*4096 + xi]);
          unsigned short hi = f2bf(xs[(size_t)(ci0+2*j+1)*4096 + xi]);
          pk[j] = (unsigned)lo | ((unsigned)hi << 16);
        }
        val = make_uint4(pk[0],pk[1],pk[2],pk[3]);
      }
      *(uint4*)(xd + (size_t)u*8) = val;
    }
  } else {
    int idx = (blk-648)*256 + t;   // 0..1,769,471
    int ci = idx & 255; int r = idx >> 8;
    int tap = r % 27, co = r / 27;
    wt[idx] = f2bf(w3[(size_t)co*6912 + ci*27 + tap]);
  }
}

// conv3d: BK=128 double-buffered LDS MFMA implicit GEMM (R16-proven, 62 us).
__global__ __launch_bounds__(512) void conv3d_dbuf(const unsigned short* __restrict__ xt,
                                                   const unsigned short* __restrict__ wt,
                                                   const unsigned short* __restrict__ hb,
                                                   const float* __restrict__ prelu_a,
                                                   const float* __restrict__ scale,
                                                   float* __restrict__ out){
  __shared__ unsigned short Wt2[2][64][136];
  __shared__ unsigned short Xt2[2][128][136];
  int bid0 = blockIdx.x;
  int bid = (bid0 & 7)*32 + (bid0 >> 3);    // bijective XCD swizzle
  int nb = (bid & 3)*64;                    // co tile
  int mb = (bid >> 2)*128;                  // m tile
  int tid = threadIdx.x;
  int l = tid & 63, w = tid >> 6;
  int lr = l & 15, lk = l >> 4;
  int w_n = w & 1, w_m = w >> 1;            // 2 x 4
  int srow = tid >> 4, sch = tid & 15;      // staging: row-base 0..31, 16B chunk 0..15
  size_t xbase[4];
  #pragma unroll
  for(int q=0;q<4;q++){
    int m = mb + q*32 + srow;
    int b = m >> 12, sp = m & 4095;
    int z = sp >> 8, y = (sp >> 4) & 15, x = sp & 15;
    xbase[q] = (size_t)(((b*18 + z+1)*18 + (y+1))*18 + (x+1))*256 + sch*8;
  }
  const unsigned short* wrow0 = wt + (size_t)(nb + srow)*6912 + sch*8;
  const unsigned short* wrow1 = wt + (size_t)(nb + 32 + srow)*6912 + sch*8;

  {
    int toff = (-324 - 18 - 1)*256;
    uint4 w0 = *(const uint4*)(wrow0);
    uint4 w1 = *(const uint4*)(wrow1);
    uint4 x0 = *(const uint4*)(xt + xbase[0] + toff);
    uint4 x1 = *(const uint4*)(xt + xbase[1] + toff);
    uint4 x2 = *(const uint4*)(xt + xbase[2] + toff);
    uint4 x3 = *(const uint4*)(xt + xbase[3] + toff);
    *(uint4*)&Wt2[0][srow   ][sch*8] = w0;
    *(uint4*)&Wt2[0][srow+32][sch*8] = w1;
    *(uint4*)&Xt2[0][srow    ][sch*8] = x0;
    *(uint4*)&Xt2[0][srow+32 ][sch*8] = x1;
    *(uint4*)&Xt2[0][srow+64 ][sch*8] = x2;
    *(uint4*)&Xt2[0][srow+96 ][sch*8] = x3;
  }
  __syncthreads();

  f32x4 acc[2][2] = {};
  int cur = 0;
  for(int s=0; s<54; ++s){
    uint4 wv0, wv1, xv0, xv1, xv2, xv3;
    if(s < 53){
      int sn = s+1;
      int tap = sn >> 1, h = sn & 1;
      int gz = tap/9; int rm = tap - gz*9; int gy = rm/3, gx = rm - gy*3;
      int toff = ((gz-1)*324 + (gy-1)*18 + (gx-1))*256 + h*128;
      int kco = tap*256 + h*128;
      wv0 = *(const uint4*)(wrow0 + kco);
      wv1 = *(const uint4*)(wrow1 + kco);
      xv0 = *(const uint4*)(xt + xbase[0] + toff);
      xv1 = *(const uint4*)(xt + xbase[1] + toff);
      xv2 = *(const uint4*)(xt + xbase[2] + toff);
      xv3 = *(const uint4*)(xt + xbase[3] + toff);
    }
    #pragma unroll
    for(int kk=0;kk<4;kk++){
      short8 af[2], bf[2];
      #pragma unroll
      for(int i=0;i<2;i++) af[i] = *(const short8*)&Wt2[cur][w_n*32+i*16+lr][kk*32+lk*8];
      #pragma unroll
      for(int j=0;j<2;j++) bf[j] = *(const short8*)&Xt2[cur][w_m*32+j*16+lr][kk*32+lk*8];
      #pragma unroll
      for(int i=0;i<2;i++)
        #pragma unroll
        for(int j=0;j<2;j++)
          acc[i][j] = __builtin_amdgcn_mfma_f32_16x16x32_bf16(af[i], bf[j], acc[i][j], 0,0,0);
    }
    if(s < 53){
      int nbuf = cur ^ 1;
      *(uint4*)&Wt2[nbuf][srow   ][sch*8] = wv0;
      *(uint4*)&Wt2[nbuf][srow+32][sch*8] = wv1;
      *(uint4*)&Xt2[nbuf][srow    ][sch*8] = xv0;
      *(uint4*)&Xt2[nbuf][srow+32 ][sch*8] = xv1;
      *(uint4*)&Xt2[nbuf][srow+64 ][sch*8] = xv2;
      *(uint4*)&Xt2[nbuf][srow+96 ][sch*8] = xv3;
      __syncthreads();
      cur = nbuf;
    }
  }

  float spv = sp_f(scale[0]);
  float pa = prelu_a[0];
  #pragma unroll
  for(int i=0;i<2;i++){
    #pragma unroll
    for(int j=0;j<2;j++){
      int m = mb + w_m*32 + j*16 + lr;
      int bb = m >> 12, sp = m & 4095;
      #pragma unroll
      for(int r=0;r<4;r++){
        int co = nb + w_n*32 + i*16 + 4*lk + r;
        float cval = acc[i][j][r];
        float pr = cval > 0.f ? cval : pa*cval;
        out[((size_t)(bb*256 + co))*4096 + sp] = bf2f(hb[(size_t)m*256 + co]) + spv*pr;
      }
    }
  }
}

extern "C" void kernel_launch(void* const* d_in, const int* in_sizes, int n_in,
                              void* d_out, int out_size, void* d_ws, size_t ws_size,
                              hipStream_t stream) {
  const float* x         = (const float*)d_in[0];
  const float* ln_w      = (const float*)d_in[1];
  const float* ln_b      = (const float*)d_in[2];
  const float* in_proj_w = (const float*)d_in[3];
  const float* conv_w    = (const float*)d_in[4];
  const float* conv_b    = (const float*)d_in[5];
  const float* x_proj_w  = (const float*)d_in[6];
  const float* dt_proj_w = (const float*)d_in[7];
  const float* dt_proj_b = (const float*)d_in[8];
  const float* A_log     = (const float*)d_in[9];
  const float* D_skip    = (const float*)d_in[10];
  const float* out_proj_w= (const float*)d_in[11];
  const float* conv3d_w  = (const float*)d_in[12];
  const float* prelu_a   = (const float*)d_in[13];
  const float* scale     = (const float*)d_in[14];
  float* out = (float*)d_out;

  // workspace layout (float offsets) — one producer per phase (R19-proven).
  float* ws   = (float*)d_ws;
  float* Ap   = ws;                               // 2,097,152 fl
  float* Ep   = Ap + 2097152;                     // 2,097,152 fl
  unsigned short* xz_bf = (unsigned short*)(Ep + 2097152);     // 8,388,608 bf16
  unsigned short* u_bf  = xz_bf + 8388608;        // 4,194,304 bf16
  float* xdbl = (float*)(u_bf + 4194304);         // 262,144 fl
  unsigned short* dt_bf = (unsigned short*)(xdbl + 262144);    // 4,194,304 bf16
  unsigned short* h_bf  = dt_bf + 4194304;        // 2,097,152 bf16 (LIVE at conv time)
  unsigned short* y_bf  = h_bf + 2097152;         // 4,194,304 bf16
  unsigned short* inw_bf   = y_bf + 4194304;      // 524,288 bf16
  unsigned short* ow_bf    = inw_bf + 524288;     // 262,144 bf16
  unsigned short* wdtx_bf  = ow_bf + 262144;      // 589,824 bf16 (2 x 576 x 512)
  const size_t base_floats = 16678912;            // 66,715,648 bytes
  // xt/wt tail: end = 76,226,560 B <= 77,070,336 B (proven)
  unsigned short* xt = (unsigned short*)(ws + base_floats);
  unsigned short* wt = xt + 2985984;

  // ---- fused weight prep ----
  prep_weights<<<5376, 256, 0, stream>>>(in_proj_w, out_proj_w, dt_proj_w, x_proj_w,
                                         inw_bf, ow_bf, wdtx_bf);

  ln_kernel<<<256, 256, 0, stream>>>(x, ln_w, ln_b, h_bf);

  for(int dep=0; dep<2; dep++){
    const unsigned short* inw  = inw_bf  + (size_t)dep*262144;
    const unsigned short* oww  = ow_bf   + (size_t)dep*131072;
    const unsigned short* wdtx = wdtx_bf + (size_t)dep*294912;
    const float* cw   = conv_w    + (size_t)dep*512*4;
    const float* cb   = conv_b    + (size_t)dep*512;
    const float* dtb  = dt_proj_b + (size_t)dep*512;
    const float* Alg  = A_log     + (size_t)dep*512*16;
    const float* Dsk  = D_skip    + (size_t)dep*512;

    // in_proj: xz_bf[8192,1024] = h_bf @ inw^T   (16 x 64 = 1024 blocks)
    gemm_lds<4,0,0,1><<<dim3(16,64), 256, 0, stream>>>(
        h_bf, inw, nullptr, nullptr, xz_bf, 8192, 1024, 256);
    conv1d_silu_kernel<<<16384, 256, 0, stream>>>(xz_bf, cw, cb, u_bf);
    // merged dt + x_proj: dt_bf + xdbl from one pass over u  (9 x 64 = 576 blocks)
    gemm_dtx<<<dim3(9,64), 256, 0, stream>>>(u_bf, wdtx, dtb, dt_bf, xdbl);

    scan_pass1<<<512, 256, 0, stream>>>(dt_bf, u_bf, xdbl, Alg, Ap, Ep);
    scan_pass2<<<64, 256, 0, stream>>>(Ap, Ep);
    scan_pass3<<<512, 256, 0, stream>>>(dt_bf, u_bf, xz_bf, xdbl, Alg, Ep, Dsk, y_bf);

    // out_proj: h_bf[8192,256] = y_bf @ ow^T  (BM=64: 4 x 128 = 512 blocks, 2/CU)
    gemm_lds<2,0,0,1><<<dim3(4,128), 256, 0, stream>>>(
        y_bf, oww, nullptr, nullptr, h_bf, 8192, 256, 512);
  }

  // conv3d: fused prep + BK=128 double-buffered MFMA conv with fused epilogue
  conv_prep<<<7560, 256, 0, stream>>>(x, conv3d_w, xt, wt);
  conv3d_dbuf<<<256, 512, 0, stream>>>(xt, wt, h_bf, prelu_a, scale, out);
}

// Round 24
// 372.375 us; speedup vs baseline: 1.1880x; 1.0025x over previous
//
#include <hip/hip_runtime.h>
#include <math.h>

#define LSEQ 4096
#define DIMC 256
#define DI   512
#define NCH  128    // chunks over L
#define CHL  32     // chunk length

typedef short short8 __attribute__((ext_vector_type(8)));
typedef float f32x4 __attribute__((ext_vector_type(4)));

__device__ __forceinline__ float sp_f(float v){ return fmaxf(v,0.f) + log1pf(__expf(-fabsf(v))); }
__device__ __forceinline__ float silu_f(float v){ return v/(1.f+__expf(-v)); }
__device__ __forceinline__ unsigned short f2bf(float f){
  unsigned u = __builtin_bit_cast(unsigned, f);
  unsigned r = (u + 0x7FFFu + ((u>>16)&1u)) >> 16;
  return (unsigned short)r;
}
__device__ __forceinline__ float bf2f(unsigned short us){
  unsigned u = ((unsigned)us)<<16;
  return __builtin_bit_cast(float, u);
}

// ---------------- LayerNorm via LDS transpose (R19-proven) ---------------------------
__global__ __launch_bounds__(256) void ln_kernel(const float* __restrict__ x,
                                                 const float* __restrict__ w,
                                                 const float* __restrict__ bias,
                                                 unsigned short* __restrict__ hb){
  __shared__ float tile[256][33];
  __shared__ float red_s[8][32];
  __shared__ float red_q[8][32];
  __shared__ float mv_mu[32], mv_rs[32];
  int bid = blockIdx.x;            // 256 = b(2) x ltile(128)
  int b = bid >> 7, l0 = (bid & 127)*32;
  int tid = threadIdx.x;
  int cc = tid >> 5, ll = tid & 31;
  const float* xb = x + (size_t)b*DIMC*LSEQ + l0 + ll;
  #pragma unroll 4
  for(int ci=0; ci<32; ci++){
    int c = ci*8 + cc;
    tile[c][ll] = xb[(size_t)c*LSEQ];
  }
  __syncthreads();
  {
    int part = tid >> 5, l = tid & 31;
    float s=0.f, sq=0.f;
    #pragma unroll
    for(int i=0;i<32;i++){ float v = tile[part*32+i][l]; s+=v; sq+=v*v; }
    red_s[part][l]=s; red_q[part][l]=sq;
  }
  __syncthreads();
  if(tid < 32){
    float s=0.f, sq=0.f;
    #pragma unroll
    for(int p=0;p<8;p++){ s+=red_s[p][tid]; sq+=red_q[p][tid]; }
    float mu = s*(1.f/256.f);
    float var = sq*(1.f/256.f) - mu*mu;
    mv_mu[tid]=mu; mv_rs[tid]=rsqrtf(var + 1e-5f);
  }
  __syncthreads();
  int cl = tid & 63, lo = tid >> 6;
  #pragma unroll
  for(int li=0; li<8; li++){
    int l = li*4 + lo;
    float mu = mv_mu[l], rs = mv_rs[l];
    unsigned short* hr = hb + (size_t)(b*4096 + l0 + l)*256;
    #pragma unroll
    for(int c2=0; c2<4; c2++){
      int c = c2*64 + cl;
      hr[c] = f2bf((tile[c][l]-mu)*rs*w[c] + bias[c]);
    }
  }
}

// ---------------- fused weight prep: 5376 blocks, block-range branching --------------
__global__ __launch_bounds__(256) void prep_weights(const float* __restrict__ in_proj_w,
                                                    const float* __restrict__ out_proj_w,
                                                    const float* __restrict__ dtw,
                                                    const float* __restrict__ xpw,
                                                    unsigned short* __restrict__ inw_bf,
                                                    unsigned short* __restrict__ ow_bf,
                                                    unsigned short* __restrict__ wdtx){
  int blk = blockIdx.x, tid = threadIdx.x;
  if(blk < 2048){
    int i = blk*256 + tid;
    inw_bf[i] = f2bf(in_proj_w[i]);
  } else if(blk < 3072){
    int i = (blk-2048)*256 + tid;
    ow_bf[i] = f2bf(out_proj_w[i]);
  } else if(blk < 5120){
    int idx = (blk-3072)*256 + tid;        // 0..524287
    int dep = idx >> 18;
    int r = idx & 262143;
    int n = r >> 9, k = r & 511;
    const float* dw = dtw + (size_t)dep*512*16 + n*16;
    const float* xp = xpw + (size_t)dep*48*512 + k;
    float acc = 0.f;
    #pragma unroll
    for(int j=0;j<16;j++) acc += dw[j] * xp[(size_t)j*512];
    wdtx[(size_t)dep*294912 + r] = f2bf(acc);
  } else if(blk < 5248){
    int i = (blk-5120)*256 + tid;          // 0..32767
    int dep = i >> 14, j = i & 16383;
    wdtx[(size_t)dep*294912 + 262144 + j] = f2bf(xpw[(size_t)dep*48*512 + 16*512 + j]);
  } else {
    int i = (blk-5248)*256 + tid;          // 0..32767
    int dep = i >> 14, j = i & 16383;
    wdtx[(size_t)dep*294912 + 278528 + j] = 0;
  }
}

// ---------------- LDS-staged bf16 MFMA GEMM, BM = QM*32 (R14-proven structure) ------
template<int QM,int EPI,int WF,int WB>
__global__ __launch_bounds__(256) void gemm_lds(
    const unsigned short* __restrict__ A,   // M x K (m rows, B-operand)
    const unsigned short* __restrict__ W,   // N x K (n rows, A-operand)
    const float* __restrict__ bias,
    float* __restrict__ Cf,
    unsigned short* __restrict__ Cb,
    int M, int N, int K){
  __shared__ unsigned short Wt[64][72];
  __shared__ unsigned short Xt[QM*32][72];
  int tid = threadIdx.x;
  int l = tid & 63, w = tid >> 6;
  int lr = l & 15, lk = l >> 4;
  int w_n = w & 1, w_m = w >> 1;
  int nb = blockIdx.x * 64;
  int mb = blockIdx.y * (QM*32);
  int srow = tid >> 3, sc8 = tid & 7;       // staging: 8 threads/row, 16B each
  f32x4 acc[2][QM] = {};
  for(int k0 = 0; k0 < K; k0 += 64){
    __syncthreads();
    #pragma unroll
    for(int q=0;q<2;q++){
      int row = q*32 + srow;
      *(uint4*)&Wt[row][sc8*8] = *(const uint4*)(W + (size_t)(nb+row)*K + k0 + sc8*8);
    }
    #pragma unroll
    for(int q=0;q<QM;q++){
      int row = q*32 + srow;
      *(uint4*)&Xt[row][sc8*8] = *(const uint4*)(A + (size_t)(mb+row)*K + k0 + sc8*8);
    }
    __syncthreads();
    #pragma unroll
    for(int kk=0;kk<2;kk++){
      short8 af[2], bf[QM];
      #pragma unroll
      for(int i=0;i<2;i++) af[i] = *(const short8*)&Wt[w_n*32+i*16+lr][kk*32+lk*8];
      #pragma unroll
      for(int j=0;j<QM;j++) bf[j] = *(const short8*)&Xt[w_m*(QM*16)+j*16+lr][kk*32+lk*8];
      #pragma unroll
      for(int i=0;i<2;i++)
        #pragma unroll
        for(int j=0;j<QM;j++)
          acc[i][j] = __builtin_amdgcn_mfma_f32_16x16x32_bf16(af[i], bf[j], acc[i][j], 0,0,0);
    }
  }
  #pragma unroll
  for(int i=0;i<2;i++){
    #pragma unroll
    for(int j=0;j<QM;j++){
      int m = mb + w_m*(QM*16) + j*16 + lr;
      #pragma unroll
      for(int r=0;r<4;r++){
        int n = nb + w_n*32 + i*16 + 4*lk + r;
        float v = acc[i][j][r];
        if(EPI==1) v = sp_f(v + bias[n]);
        if(WF) Cf[(size_t)m*N + n] = v;
        if(WB) Cb[(size_t)m*N + n] = f2bf(v);
      }
    }
  }
}

// ---------------- merged dt + x_proj GEMM over wdtx[576][512] (R19-proven) ----------
__global__ __launch_bounds__(256) void gemm_dtx(
    const unsigned short* __restrict__ A,    // u_bf, 8192 x 512
    const unsigned short* __restrict__ W,    // wdtx, 576 x 512
    const float* __restrict__ dtb,
    unsigned short* __restrict__ dtb_out,    // dt_bf
    float* __restrict__ xdbl){
  __shared__ unsigned short Wt[64][72];
  __shared__ unsigned short Xt[128][72];
  int tid = threadIdx.x;
  int l = tid & 63, w = tid >> 6;
  int lr = l & 15, lk = l >> 4;
  int w_n = w & 1, w_m = w >> 1;
  int nb = blockIdx.x * 64;
  int mb = blockIdx.y * 128;
  int srow = tid >> 3, sc8 = tid & 7;
  f32x4 acc[2][4] = {};
  for(int k0 = 0; k0 < 512; k0 += 64){
    __syncthreads();
    #pragma unroll
    for(int q=0;q<2;q++){
      int row = q*32 + srow;
      *(uint4*)&Wt[row][sc8*8] = *(const uint4*)(W + (size_t)(nb+row)*512 + k0 + sc8*8);
    }
    #pragma unroll
    for(int q=0;q<4;q++){
      int row = q*32 + srow;
      *(uint4*)&Xt[row][sc8*8] = *(const uint4*)(A + (size_t)(mb+row)*512 + k0 + sc8*8);
    }
    __syncthreads();
    #pragma unroll
    for(int kk=0;kk<2;kk++){
      short8 af[2], bf[4];
      #pragma unroll
      for(int i=0;i<2;i++) af[i] = *(const short8*)&Wt[w_n*32+i*16+lr][kk*32+lk*8];
      #pragma unroll
      for(int j=0;j<4;j++) bf[j] = *(const short8*)&Xt[w_m*64+j*16+lr][kk*32+lk*8];
      #pragma unroll
      for(int i=0;i<2;i++)
        #pragma unroll
        for(int j=0;j<4;j++)
          acc[i][j] = __builtin_amdgcn_mfma_f32_16x16x32_bf16(af[i], bf[j], acc[i][j], 0,0,0);
    }
  }
  #pragma unroll
  for(int i=0;i<2;i++){
    #pragma unroll
    for(int j=0;j<4;j++){
      int m = mb + w_m*64 + j*16 + lr;
      #pragma unroll
      for(int r=0;r<4;r++){
        int n = nb + w_n*32 + i*16 + 4*lk + r;
        float v = acc[i][j][r];
        if(n < 512){
          dtb_out[(size_t)m*512 + n] = f2bf(sp_f(v + dtb[n]));
        } else if(n < 544){
          xdbl[(size_t)m*32 + (n-512)] = v;
        }
      }
    }
  }
}

// ---------------- causal depthwise conv1d (k=4) + bias + SiLU (xz bf16) -> u_bf -----
__global__ __launch_bounds__(256) void conv1d_silu_kernel(const unsigned short* __restrict__ xz,
                                                          const float* __restrict__ cw,
                                                          const float* __restrict__ cb,
                                                          unsigned short* __restrict__ ub){
  int g = blockIdx.x*256 + threadIdx.x;   // b*2^21 + l*512 + d
  int d = g & 511;
  int l = (g>>9) & 4095;
  int b = g >> 21;
  const unsigned short* up = xz + (size_t)b*LSEQ*1024 + d;
  float accv = cb[d];
  #pragma unroll
  for(int k=0;k<4;k++){
    int ls = l-3+k;
    float vv = (ls>=0) ? bf2f(up[(size_t)ls*1024]) : 0.f;
    accv += vv * cw[d*4+k];
  }
  ub[(size_t)g] = f2bf(silu_f(accv));
}

// ================= chunked selective scan, 16 states in registers (R16-proven) ======
__global__ __launch_bounds__(256) void scan_pass1(const unsigned short* __restrict__ dt,
                                                  const unsigned short* __restrict__ u,
                                                  const float* __restrict__ xdbl,
                                                  const float* __restrict__ A_log,
                                                  float* __restrict__ Ap,
                                                  float* __restrict__ Ep){
  __shared__ float bc[CHL*32];
  int bid = blockIdx.x;            // 512 = b(2) x ch(128) x dh(2)
  int b = bid >> 8, ch = (bid >> 1) & 127, dh = bid & 1;
  int tid = threadIdx.x;
  int d = dh*256 + tid;
  int row0 = b*4096 + ch*CHL;
  *(float4*)&bc[tid*4] = *(const float4*)&xdbl[(size_t)row0*32 + tid*4];
  __syncthreads();
  float a[16];
  #pragma unroll
  for(int s=0;s<16;s++) a[s] = -__expf(A_log[d*16+s]);
  float h[16];
  #pragma unroll
  for(int s=0;s<16;s++) h[s] = 0.f;
  float sumdt = 0.f;
  const unsigned short* dtp = dt + (size_t)row0*512 + d;
  const unsigned short* up  = u  + (size_t)row0*512 + d;
  for(int t=0;t<CHL;t++){
    float dtv = bf2f(dtp[(size_t)t*512]);
    float uv  = bf2f(up[(size_t)t*512]);
    float dtbu = dtv*uv;
    sumdt += dtv;
    #pragma unroll
    for(int s=0;s<16;s++){
      float dA = __expf(a[s]*dtv);
      h[s] = dA*h[s] + dtbu*bc[t*32+s];
    }
  }
  int bd = b*512 + d;
  #pragma unroll
  for(int s=0;s<16;s++){
    Ap[(size_t)ch*16384 + s*1024 + bd] = __expf(a[s]*sumdt);
    Ep[(size_t)ch*16384 + s*1024 + bd] = h[s];
  }
}

// exclusive scan over chunks; unroll-4 with batched loads for latency overlap
__global__ __launch_bounds__(256) void scan_pass2(const float* __restrict__ Ap,
                                                  float* __restrict__ Ep){
  int idx = blockIdx.x*256 + threadIdx.x;   // 0..16383
  float h = 0.f;
  for(int c=0;c<NCH;c+=4){
    float a0 = Ap[(size_t)(c+0)*16384 + idx];
    float a1 = Ap[(size_t)(c+1)*16384 + idx];
    float a2 = Ap[(size_t)(c+2)*16384 + idx];
    float a3 = Ap[(size_t)(c+3)*16384 + idx];
    float e0 = Ep[(size_t)(c+0)*16384 + idx];
    float e1 = Ep[(size_t)(c+1)*16384 + idx];
    float e2 = Ep[(size_t)(c+2)*16384 + idx];
    float e3 = Ep[(size_t)(c+3)*16384 + idx];
    Ep[(size_t)(c+0)*16384 + idx] = h; h = a0*h + e0;
    Ep[(size_t)(c+1)*16384 + idx] = h; h = a1*h + e1;
    Ep[(size_t)(c+2)*16384 + idx] = h; h = a2*h + e2;
    Ep[(size_t)(c+3)*16384 + idx] = h; h = a3*h + e3;
  }
}

__global__ __launch_bounds__(256) void scan_pass3(const unsigned short* __restrict__ dt,
                                                  const unsigned short* __restrict__ u,
                                                  const unsigned short* __restrict__ xz,
                                                  const float* __restrict__ xdbl,
                                                  const float* __restrict__ A_log,
                                                  const float* __restrict__ Ep,
                                                  const float* __restrict__ Dsk,
                                                  unsigned short* __restrict__ yb){
  __shared__ float bc[CHL*32];
  int bid = blockIdx.x;            // 512 = b(2) x ch(128) x dh(2)
  int b = bid >> 8, ch = (bid >> 1) & 127, dh = bid & 1;
  int tid = threadIdx.x;
  int d = dh*256 + tid;
  int row0 = b*4096 + ch*CHL;
  *(float4*)&bc[tid*4] = *(const float4*)&xdbl[(size_t)row0*32 + tid*4];
  __syncthreads();
  float a[16];
  #pragma unroll
  for(int s=0;s<16;s++) a[s] = -__expf(A_log[d*16+s]);
  int bd = b*512 + d;
  float h[16];
  #pragma unroll
  for(int s=0;s<16;s++) h[s] = Ep[(size_t)ch*16384 + s*1024 + bd];
  float dskv = Dsk[d];
  const unsigned short* dtp = dt + (size_t)row0*512 + d;
  const unsigned short* up  = u  + (size_t)row0*512 + d;
  const unsigned short* zp  = xz + (size_t)row0*1024 + 512 + d;
  unsigned short* yp = yb + (size_t)row0*512 + d;
  for(int t=0;t<CHL;t++){
    float dtv = bf2f(dtp[(size_t)t*512]);
    float uv  = bf2f(up[(size_t)t*512]);
    float dtbu = dtv*uv;
    float y = 0.f;
    #pragma unroll
    for(int s=0;s<16;s++){
      float dA = __expf(a[s]*dtv);
      h[s] = dA*h[s] + dtbu*bc[t*32+s];
      y += h[s]*bc[t*32+16+s];
    }
    float z = bf2f(zp[(size_t)t*1024]);
    yp[(size_t)t*512] = f2bf((y + uv*dskv) * silu_f(z));
  }
}

// ================= conv3d prep: fused xt_fill + wt_conv (7560 blocks) ===============
__global__ __launch_bounds__(256) void conv_prep(const float* __restrict__ x,
                                                 const float* __restrict__ w3,
                                                 unsigned short* __restrict__ xt,
                                                 unsigned short* __restrict__ wt){
  int blk = blockIdx.x, t = threadIdx.x;
  if(blk < 648){
    int b = blk / 324; int r = blk - b*324;
    int zz = r / 18, yy = r - zz*18;
    bool inner = (zz>=1 && zz<=16 && yy>=1 && yy<=16);
    unsigned short* xd = xt + (size_t)((b*18 + zz)*18 + yy)*18*256;
    const float* xs = x + (size_t)b*256*4096 + (zz-1)*256 + (yy-1)*16;
    for(int u = t; u < 576; u += 256){
      int xpos = u >> 5;           // 0..17
      int ci0 = (u & 31) * 8;
      uint4 val = make_uint4(0,0,0,0);
      if(inner && xpos>=1 && xpos<=16){
        int xi = xpos-1;
        unsigned pk[4];
        #pragma unroll
        for(int j=0;j<4;j++){
          unsigned short lo = f2bf(xs[(size_t)(ci0+2*j  )*4096 + xi]);
          unsigned short hi = f2bf(xs[(size_t)(ci0+2*j+1)*4096 + xi]);
          pk[j] = (unsigned)lo | ((unsigned)hi << 16);
        }
        val = make_uint4(pk[0],pk[1],pk[2],pk[3]);
      }
      *(uint4*)(xd + (size_t)u*8) = val;
    }
  } else {
    int idx = (blk-648)*256 + t;   // 0..1,769,471
    int ci = idx & 255; int r = idx >> 8;
    int tap = r % 27, co = r / 27;
    wt[idx] = f2bf(w3[(size_t)co*6912 + ci*27 + tap]);
  }
}

// conv3d: BK=128 double-buffered LDS MFMA implicit GEMM, split to 512 blocks x 256 thr
// (BM=64): 69.6 KB LDS -> 2 independent blocks/CU, decoupled barrier domains.
// 4 waves = 2(co-32) x 2(m-32); 54 steps, one barrier each; fused prelu+skip epilogue.
__global__ __launch_bounds__(256) void conv3d_dbuf(const unsigned short* __restrict__ xt,
                                                   const unsigned short* __restrict__ wt,
                                                   const unsigned short* __restrict__ hb,
                                                   const float* __restrict__ prelu_a,
                                                   const float* __restrict__ scale,
                                                   float* __restrict__ out){
  __shared__ unsigned short Wt2[2][64][136];
  __shared__ unsigned short Xt2[2][64][136];
  int bid0 = blockIdx.x;
  int bid = (bid0 & 7)*64 + (bid0 >> 3);    // bijective XCD swizzle (512 = 8*64)
  int nb = (bid & 3)*64;                    // co tile
  int mb = (bid >> 2)*64;                   // m tile (64 each, 128 tiles)
  int tid = threadIdx.x;
  int l = tid & 63, w = tid >> 6;
  int lr = l & 15, lk = l >> 4;
  int w_n = w & 1, w_m = w >> 1;            // 2 x 2 waves
  int srow = tid >> 4, sch = tid & 15;      // staging: row-base 0..15, 16B chunk 0..15
  size_t xbase[4];
  const unsigned short* wrow[4];
  #pragma unroll
  for(int q=0;q<4;q++){
    int m = mb + q*16 + srow;
    int b = m >> 12, sp = m & 4095;
    int z = sp >> 8, y = (sp >> 4) & 15, x = sp & 15;
    xbase[q] = (size_t)(((b*18 + z+1)*18 + (y+1))*18 + (x+1))*256 + sch*8;
    wrow[q] = wt + (size_t)(nb + q*16 + srow)*6912 + sch*8;
  }

  // prologue: stage step 0 (tap 0, half 0) into buf 0
  {
    int toff = (-324 - 18 - 1)*256;
    uint4 wv[4], xv[4];
    #pragma unroll
    for(int q=0;q<4;q++){ wv[q] = *(const uint4*)(wrow[q]); xv[q] = *(const uint4*)(xt + xbase[q] + toff); }
    #pragma unroll
    for(int q=0;q<4;q++){
      *(uint4*)&Wt2[0][q*16+srow][sch*8] = wv[q];
      *(uint4*)&Xt2[0][q*16+srow][sch*8] = xv[q];
    }
  }
  __syncthreads();

  f32x4 acc[2][2] = {};
  int cur = 0;
  for(int s=0; s<54; ++s){
    uint4 wv[4], xv[4];
    if(s < 53){
      int sn = s+1;
      int tap = sn >> 1, h = sn & 1;
      int gz = tap/9; int rm = tap - gz*9; int gy = rm/3, gx = rm - gy*3;
      int toff = ((gz-1)*324 + (gy-1)*18 + (gx-1))*256 + h*128;
      int kco = tap*256 + h*128;
      #pragma unroll
      for(int q=0;q<4;q++){
        wv[q] = *(const uint4*)(wrow[q] + kco);
        xv[q] = *(const uint4*)(xt + xbase[q] + toff);
      }
    }
    #pragma unroll
    for(int kk=0;kk<4;kk++){
      short8 af[2], bf[2];
      #pragma unroll
      for(int i=0;i<2;i++) af[i] = *(const short8*)&Wt2[cur][w_n*32+i*16+lr][kk*32+lk*8];
      #pragma unroll
      for(int j=0;j<2;j++) bf[j] = *(const short8*)&Xt2[cur][w_m*32+j*16+lr][kk*32+lk*8];
      #pragma unroll
      for(int i=0;i<2;i++)
        #pragma unroll
        for(int j=0;j<2;j++)
          acc[i][j] = __builtin_amdgcn_mfma_f32_16x16x32_bf16(af[i], bf[j], acc[i][j], 0,0,0);
    }
    if(s < 53){
      int nbuf = cur ^ 1;
      #pragma unroll
      for(int q=0;q<4;q++){
        *(uint4*)&Wt2[nbuf][q*16+srow][sch*8] = wv[q];
        *(uint4*)&Xt2[nbuf][q*16+srow][sch*8] = xv[q];
      }
      __syncthreads();
      cur = nbuf;
    }
  }

  float spv = sp_f(scale[0]);
  float pa = prelu_a[0];
  #pragma unroll
  for(int i=0;i<2;i++){
    #pragma unroll
    for(int j=0;j<2;j++){
      int m = mb + w_m*32 + j*16 + lr;
      int bb = m >> 12, sp = m & 4095;
      #pragma unroll
      for(int r=0;r<4;r++){
        int co = nb + w_n*32 + i*16 + 4*lk + r;
        float cval = acc[i][j][r];
        float pr = cval > 0.f ? cval : pa*cval;
        out[((size_t)(bb*256 + co))*4096 + sp] = bf2f(hb[(size_t)m*256 + co]) + spv*pr;
      }
    }
  }
}

extern "C" void kernel_launch(void* const* d_in, const int* in_sizes, int n_in,
                              void* d_out, int out_size, void* d_ws, size_t ws_size,
                              hipStream_t stream) {
  const float* x         = (const float*)d_in[0];
  const float* ln_w      = (const float*)d_in[1];
  const float* ln_b      = (const float*)d_in[2];
  const float* in_proj_w = (const float*)d_in[3];
  const float* conv_w    = (const float*)d_in[4];
  const float* conv_b    = (const float*)d_in[5];
  const float* x_proj_w  = (const float*)d_in[6];
  const float* dt_proj_w = (const float*)d_in[7];
  const float* dt_proj_b = (const float*)d_in[8];
  const float* A_log     = (const float*)d_in[9];
  const float* D_skip    = (const float*)d_in[10];
  const float* out_proj_w= (const float*)d_in[11];
  const float* conv3d_w  = (const float*)d_in[12];
  const float* prelu_a   = (const float*)d_in[13];
  const float* scale     = (const float*)d_in[14];
  float* out = (float*)d_out;

  // workspace layout (float offsets) — one producer per phase (R19-proven).
  float* ws   = (float*)d_ws;
  float* Ap   = ws;                               // 2,097,152 fl
  float* Ep   = Ap + 2097152;                     // 2,097,152 fl
  unsigned short* xz_bf = (unsigned short*)(Ep + 2097152);     // 8,388,608 bf16
  unsigned short* u_bf  = xz_bf + 8388608;        // 4,194,304 bf16
  float* xdbl = (float*)(u_bf + 4194304);         // 262,144 fl
  unsigned short* dt_bf = (unsigned short*)(xdbl + 262144);    // 4,194,304 bf16
  unsigned short* h_bf  = dt_bf + 4194304;        // 2,097,152 bf16 (LIVE at conv time)
  unsigned short* y_bf  = h_bf + 2097152;         // 4,194,304 bf16
  unsigned short* inw_bf   = y_bf + 4194304;      // 524,288 bf16
  unsigned short* ow_bf    = inw_bf + 524288;     // 262,144 bf16
  unsigned short* wdtx_bf  = ow_bf + 262144;      // 589,824 bf16 (2 x 576 x 512)
  const size_t base_floats = 16678912;            // 66,715,648 bytes
  // xt/wt tail: end = 76,226,560 B <= 77,070,336 B (proven)
  unsigned short* xt = (unsigned short*)(ws + base_floats);
  unsigned short* wt = xt + 2985984;

  // ---- fused weight prep ----
  prep_weights<<<5376, 256, 0, stream>>>(in_proj_w, out_proj_w, dt_proj_w, x_proj_w,
                                         inw_bf, ow_bf, wdtx_bf);

  ln_kernel<<<256, 256, 0, stream>>>(x, ln_w, ln_b, h_bf);

  for(int dep=0; dep<2; dep++){
    const unsigned short* inw  = inw_bf  + (size_t)dep*262144;
    const unsigned short* oww  = ow_bf   + (size_t)dep*131072;
    const unsigned short* wdtx = wdtx_bf + (size_t)dep*294912;
    const float* cw   = conv_w    + (size_t)dep*512*4;
    const float* cb   = conv_b    + (size_t)dep*512;
    const float* dtb  = dt_proj_b + (size_t)dep*512;
    const float* Alg  = A_log     + (size_t)dep*512*16;
    const float* Dsk  = D_skip    + (size_t)dep*512;

    // in_proj: xz_bf[8192,1024] = h_bf @ inw^T   (16 x 64 = 1024 blocks)
    gemm_lds<4,0,0,1><<<dim3(16,64), 256, 0, stream>>>(
        h_bf, inw, nullptr, nullptr, xz_bf, 8192, 1024, 256);
    conv1d_silu_kernel<<<16384, 256, 0, stream>>>(xz_bf, cw, cb, u_bf);
    // merged dt + x_proj: dt_bf + xdbl from one pass over u  (9 x 64 = 576 blocks)
    gemm_dtx<<<dim3(9,64), 256, 0, stream>>>(u_bf, wdtx, dtb, dt_bf, xdbl);

    scan_pass1<<<512, 256, 0, stream>>>(dt_bf, u_bf, xdbl, Alg, Ap, Ep);
    scan_pass2<<<64, 256, 0, stream>>>(Ap, Ep);
    scan_pass3<<<512, 256, 0, stream>>>(dt_bf, u_bf, xz_bf, xdbl, Alg, Ep, Dsk, y_bf);

    // out_proj: h_bf[8192,256] = y_bf @ ow^T  (BM=64: 4 x 128 = 512 blocks, 2/CU)
    gemm_lds<2,0,0,1><<<dim3(4,128), 256, 0, stream>>>(
        y_bf, oww, nullptr, nullptr, h_bf, 8192, 256, 512);
  }

  // conv3d: fused prep + BK=128 dbuf MFMA conv, 512 x 256 (2 blocks/CU)
  conv_prep<<<7560, 256, 0, stream>>>(x, conv3d_w, xt, wt);
  conv3d_dbuf<<<512, 256, 0, stream>>>(xt, wt, h_bf, prelu_a, scale, out);
}